// Round 4
// baseline (318.556 us; speedup 1.0000x reference)
//
#include <hip/hip_runtime.h>

// Causal depthwise conv1d: y[b,s,h] = sum_j x[b, s-(K-1)+j, h] * w[h,j], * mask[b,s]
// B=4, S=4096, H=2048, K=4, fp32. Memory-bound.
//
// History: R2/R3/R5/R6 all pinned at 2.6-2.75 TB/s (copy ceiling: 6.3).
// R6 falsified occupancy theory (occ 48->61% gave +4% BW) and the compiler
// defeated the explicit load ring (VGPR stayed 32 -> MLP stayed ~1).
// R7 theory: phase-locked STRIDED frontier. All blocks walk their T-row window in
// lockstep -> at any instant only 8KB per 64KB of address space is active (classic
// power-of-2 HBM channel imbalance). Copy kernels sweep a CONTIGUOUS frontier.
// Fix: one block per (b,s) row. 4 independent tap-row loads (MLP=4 forced by
// dataflow), 16384 blocks = 16 backfill rounds, consecutive bids = contiguous
// rolling frontier. Chunked XCD swizzle so a row's 3 halo re-reads hit the same
// XCD's L2. nt-stores keep dead y stream from evicting halo rows.
// Predict: BW 2.75 -> >=4.5 TB/s, dur -> <=50us, FETCH 90 -> 100-160MB.

constexpr int B_  = 4;
constexpr int S_  = 4096;
constexpr int H_  = 2048;
constexpr int H4_ = H_ / 4;      // 512 float4 channel-groups per (b,s) row
constexpr int TPB = 512;         // one thread per float4 group -> full row per block
constexpr int NXCD = 8;

typedef float f32x4 __attribute__((ext_vector_type(4)));  // native vec for nt-store

__global__ __launch_bounds__(TPB, 8) void budgie_dwconv1d_kernel(
    const float* __restrict__ x,     // [B,S,H]
    const float* __restrict__ w,     // [H,K]
    const float* __restrict__ mask,  // [B,S]
    float* __restrict__ y)           // [B,S,H]
{
    // Chunked XCD swizzle (bijective: S_ % NXCD == 0): hardware round-robins
    // consecutive bids across XCDs; remap so XCD k sweeps rows k*512..k*512+511
    // sequentially -> halo re-reads are same-L2 hits, frontier stays contiguous
    // per XCD chunk.
    const int bid = blockIdx.x;
    const int s   = (bid & (NXCD - 1)) * (S_ / NXCD) + (bid >> 3);
    const int b   = blockIdx.y;
    const int h4  = threadIdx.x;                 // channel-group id, 0..511

    const float4* __restrict__ x4 = (const float4*)x;
    const float4* __restrict__ w4 = (const float4*)w;
    f32x4* __restrict__ y4 = (f32x4*)y;

    // Per-channel taps: w[h, 0..3] contiguous -> one float4 per channel. L2-hot.
    const int hbase = h4 * 4;
    const float4 w0 = w4[hbase + 0];
    const float4 w1 = w4[hbase + 1];
    const float4 w2 = w4[hbase + 2];
    const float4 w3 = w4[hbase + 3];

    const long row = ((long)b * S_ + s) * H4_ + h4;   // float4-unit index, row s

    const float4 zero4 = make_float4(0.f, 0.f, 0.f, 0.f);
    // 4 INDEPENDENT loads: compiler must issue all before the FMA chain -> MLP=4.
    // s is block-uniform, so the s>=k guards are uniform branches/selects.
    const float4 xm3 = (s >= 3) ? x4[row - 3 * H4_] : zero4;
    const float4 xm2 = (s >= 2) ? x4[row - 2 * H4_] : zero4;
    const float4 xm1 = (s >= 1) ? x4[row - 1 * H4_] : zero4;
    const float4 x0  = x4[row];

    const float m = mask[b * S_ + s];            // uniform scalar -> s_load

    f32x4 o;
    o.x = fmaf(xm3.x, w0.x, fmaf(xm2.x, w0.y, fmaf(xm1.x, w0.z, x0.x * w0.w)));
    o.y = fmaf(xm3.y, w1.x, fmaf(xm2.y, w1.y, fmaf(xm1.y, w1.z, x0.y * w1.w)));
    o.z = fmaf(xm3.z, w2.x, fmaf(xm2.z, w2.y, fmaf(xm1.z, w2.z, x0.z * w2.w)));
    o.w = fmaf(xm3.w, w3.x, fmaf(xm2.w, w3.y, fmaf(xm1.w, w3.z, x0.w * w3.w)));
    o.x *= m; o.y *= m; o.z *= m; o.w *= m;

    __builtin_nontemporal_store(o, &y4[row]);
}

extern "C" void kernel_launch(void* const* d_in, const int* in_sizes, int n_in,
                              void* d_out, int out_size, void* d_ws, size_t ws_size,
                              hipStream_t stream) {
    const float* x    = (const float*)d_in[0];   // hidden_states [B,S,H]
    const float* w    = (const float*)d_in[1];   // weight [H,K]
    const float* mask = (const float*)d_in[2];   // attention_mask_2d [B,S]
    float* y = (float*)d_out;

    dim3 grid(S_, B_);                           // (4096, 4) = 16384 blocks, 16 rounds
    budgie_dwconv1d_kernel<<<grid, TPB, 0, stream>>>(x, w, mask, y);
}

// Round 5
// 231.908 us; speedup vs baseline: 1.3736x; 1.3736x over previous
//
#include <hip/hip_runtime.h>

// Causal depthwise conv1d: y[b,s,h] = sum_j x[b, s-(K-1)+j, h] * w[h,j], * mask[b,s]
// B=4, S=4096, H=2048, K=4, fp32. Memory-bound.
//
// History: R2/R3/R5/R6 pinned at 2.6-2.75 TB/s; R7 (1-row blocks) = 1.25 TB/s.
// R7 post-mortem: volume down + occupancy up + perf down => neither is the limit.
// Invariant across all ~2.6 rounds: VGPR=32 => compiler schedules load->vmcnt(0)->
// fma->store, ONE 1KB load in flight per wave (sliding-window carried dep blocks
// pipelining; R6's ring was sunk). Copy uBench (6.3 TB/s) differs only in MLP
// (~8-16 independent loads in flight/wave). R8: batch-issue ALL 11 row-loads
// (3 halo + 8 rows) upfront as independent loads, pinned by sched_barrier(0) so
// they cannot be sunk; consume with the compiler's natural vmcnt(7..0) ramp.
// launch_bounds(512,4) caps VGPR at 128 (~85 needed) -> 16 waves/CU.
// Predict: VGPR 32->~90 (gate), BW 2.75->>=4 TB/s, dur <=60us, occupancy ~45%.

constexpr int B_  = 4;
constexpr int S_  = 4096;
constexpr int H_  = 2048;
constexpr int T_  = 8;           // s-rows per block
constexpr int H4_ = H_ / 4;      // 512 float4 channel-groups per (b,s) row
constexpr int TPB = 512;         // one thread per float4 group -> full row per block

typedef float f32x4 __attribute__((ext_vector_type(4)));  // native vec for nt-store

__device__ __forceinline__ float bcast(float v) {
    // block-uniform value -> SGPR (frees VGPRs, keeps mask off the VMEM critical path)
    return __uint_as_float(__builtin_amdgcn_readfirstlane(__float_as_uint(v)));
}

__global__ __launch_bounds__(TPB, 4) void budgie_dwconv1d_kernel(
    const float* __restrict__ x,     // [B,S,H]
    const float* __restrict__ w,     // [H,K]
    const float* __restrict__ mask,  // [B,S]
    float* __restrict__ y)           // [B,S,H]
{
    const int h4 = threadIdx.x;                      // channel-group id, 0..511
    const int s0 = blockIdx.x * T_;
    const int b  = blockIdx.y;

    const float4* __restrict__ x4 = (const float4*)x;
    const float4* __restrict__ w4 = (const float4*)w;
    f32x4* __restrict__ y4 = (f32x4*)y;

    // Per-channel taps: w[h, 0..3] contiguous -> one float4 per channel. 16 VGPR.
    const int hbase = h4 * 4;
    const float4 w0 = w4[hbase + 0];
    const float4 w1 = w4[hbase + 1];
    const float4 w2 = w4[hbase + 2];
    const float4 w3 = w4[hbase + 3];

    // Masks for the 8 rows: block-uniform -> SGPRs.
    const float4* mrow = (const float4*)(mask + b * S_ + s0);
    const float4 mA = mrow[0];
    const float4 mB = mrow[1];
    const float mk[T_] = { bcast(mA.x), bcast(mA.y), bcast(mA.z), bcast(mA.w),
                           bcast(mB.x), bcast(mB.y), bcast(mB.z), bcast(mB.w) };

    const long base = (long)b * S_ * H4_ + h4;       // float4-unit index at s=0
    const float4 zero4 = make_float4(0.f, 0.f, 0.f, 0.f);

    // ---- Batch phase: 11 INDEPENDENT loads (rows s0-3 .. s0+7), all in flight.
    float4 xb[T_ + 3];                               // static indices only (full unroll)
    xb[0] = (s0 >= 3) ? x4[base + (long)(s0 - 3) * H4_] : zero4;
    xb[1] = (s0 >= 2) ? x4[base + (long)(s0 - 2) * H4_] : zero4;
    xb[2] = (s0 >= 1) ? x4[base + (long)(s0 - 1) * H4_] : zero4;
    #pragma unroll
    for (int t = 0; t < T_; ++t)
        xb[3 + t] = x4[base + (long)(s0 + t) * H4_];

    // Full scheduling fence: no load may be sunk past this point -> all 11 issue
    // before any consumption. Compiler emits a decreasing vmcnt ramp below.
    __builtin_amdgcn_sched_barrier(0);

    // ---- Consume phase: row t needs xb[t..t+3]; stores are fire-and-forget.
    #pragma unroll
    for (int t = 0; t < T_; ++t) {
        const float4 x3 = xb[t + 0];                 // x[s-3]
        const float4 x2 = xb[t + 1];                 // x[s-2]
        const float4 x1 = xb[t + 2];                 // x[s-1]
        const float4 x0 = xb[t + 3];                 // x[s]
        const float  m  = mk[t];

        f32x4 o;
        o.x = fmaf(x3.x, w0.x, fmaf(x2.x, w0.y, fmaf(x1.x, w0.z, x0.x * w0.w)));
        o.y = fmaf(x3.y, w1.x, fmaf(x2.y, w1.y, fmaf(x1.y, w1.z, x0.y * w1.w)));
        o.z = fmaf(x3.z, w2.x, fmaf(x2.z, w2.y, fmaf(x1.z, w2.z, x0.z * w2.w)));
        o.w = fmaf(x3.w, w3.x, fmaf(x2.w, w3.y, fmaf(x1.w, w3.z, x0.w * w3.w)));
        o.x *= m; o.y *= m; o.z *= m; o.w *= m;

        __builtin_nontemporal_store(o, &y4[base + (long)(s0 + t) * H4_]);
    }
}

extern "C" void kernel_launch(void* const* d_in, const int* in_sizes, int n_in,
                              void* d_out, int out_size, void* d_ws, size_t ws_size,
                              hipStream_t stream) {
    const float* x    = (const float*)d_in[0];   // hidden_states [B,S,H]
    const float* w    = (const float*)d_in[1];   // weight [H,K]
    const float* mask = (const float*)d_in[2];   // attention_mask_2d [B,S]
    float* y = (float*)d_out;

    dim3 grid(S_ / T_, B_);                      // (512, 4) = 2048 blocks
    budgie_dwconv1d_kernel<<<grid, TPB, 0, stream>>>(x, w, mask, y);
}